// Round 3
// baseline (176.111 us; speedup 1.0000x reference)
//
#include <hip/hip_runtime.h>

// OctreeConv: out[N,64] = sum_k gather_k(input)[N,32] @ W[k][32,64]
// Round 3: gather-latency attack. 256-thr blocks + 256-reg/wave budget,
// neighbor indices preloaded to registers (breaks idx->A dependent chain),
// weights staged in two k-phases (71.7KB LDS -> 2 blocks/CU).

typedef float  f32x4  __attribute__((ext_vector_type(4)));
typedef __bf16 bf16x8 __attribute__((ext_vector_type(8)));
typedef int    i32x4  __attribute__((ext_vector_type(4)));
typedef ushort u16x4  __attribute__((ext_vector_type(4)));

#define NN 262144
#define CI 32
#define CO 64
#define KK 27
#define KH 14                 // taps in phase 0 (phase 1: 13)
#define WPAD 40               // 80B rows: 16B-aligned b128 reads, low conflict
#define THREADS 256
#define TILE_T 4              // 4 A-tiles (64 octants) per wave
#define OCT_PER_BLOCK (TILE_T * 16 * (THREADS / 64))   // 256

__device__ __forceinline__ ushort f2bf_rne(float f) {
  union { float f; unsigned u; } v; v.f = f;
  unsigned u = v.u;
  u += 0x7FFFu + ((u >> 16) & 1u);
  return (ushort)(u >> 16);
}

__global__ __launch_bounds__(256) void cvt_input_kernel(
    const float* __restrict__ in, ushort* __restrict__ out) {
  const int i = (blockIdx.x * 256 + threadIdx.x) * 4;
  f32x4 v = *(const f32x4*)(in + i);
  u16x4 o;
  o[0] = f2bf_rne(v[0]); o[1] = f2bf_rne(v[1]);
  o[2] = f2bf_rne(v[2]); o[3] = f2bf_rne(v[3]);
  *(u16x4*)(out + i) = o;
}

// Stage KTAPS taps of weights (starting at kbase) into LDS as bf16 [k][o][c].
template <int KTAPS>
__device__ __forceinline__ void stage_weights(
    const float* __restrict__ weights, ushort* __restrict__ w_lds, int kbase) {
  // item = ((k*CO + o) * (CI/4) + c4); each thread: 4 f32 loads -> u16x4 ds_write
  for (int i = threadIdx.x; i < KTAPS * CO * (CI / 4); i += THREADS) {
    const int c4 = (i & 7) * 4;
    const int ko = i >> 3;          // k*CO + o
    const int k  = ko >> 6;
    const int o  = ko & 63;
    const float* wp = weights + ((size_t)(kbase + k) * CI + c4) * CO + o;
    u16x4 w;
    w[0] = f2bf_rne(wp[0 * CO]);
    w[1] = f2bf_rne(wp[1 * CO]);
    w[2] = f2bf_rne(wp[2 * CO]);
    w[3] = f2bf_rne(wp[3 * CO]);
    *(u16x4*)&w_lds[(k * CO + o) * WPAD + c4] = w;
  }
}

template <int KTAPS, bool BF16IN>
__device__ __forceinline__ void compute_phase(
    const void* __restrict__ input_v, const int* __restrict__ neigh,
    const ushort* __restrict__ w_lds, int oct_base, int kbase,
    int g, int r16, f32x4 acc[TILE_T][4]) {
  // Preload ALL neighbor indices for this phase into registers:
  // breaks the idx->A dependent chain so A-loads can be hoisted freely.
  int nb[TILE_T][KTAPS];
#pragma unroll
  for (int t = 0; t < TILE_T; ++t) {
    const int* __restrict__ nrow =
        neigh + (size_t)(oct_base + t * 16 + r16) * KK + kbase;
#pragma unroll
    for (int kk = 0; kk < KTAPS; ++kk) nb[t][kk] = nrow[kk];
  }

#pragma unroll
  for (int kk = 0; kk < KTAPS; ++kk) {
    bf16x8 bf[4];
#pragma unroll
    for (int b = 0; b < 4; ++b)
      bf[b] = *(const bf16x8*)&w_lds[(kk * CO + r16 + 16 * b) * WPAD + g * 8];

#pragma unroll
    for (int t = 0; t < TILE_T; ++t) {
      const int idx = nb[t][kk];
      bf16x8 a;
      if (BF16IN) {
        const ushort* __restrict__ ip =
            (const ushort*)input_v + (size_t)(idx < 0 ? 0 : idx) * CI + g * 8;
        i32x4 u = *(const i32x4*)ip;
        if (idx < 0) u = (i32x4){0, 0, 0, 0};
        a = __builtin_bit_cast(bf16x8, u);
      } else {
        const float* __restrict__ ip =
            (const float*)input_v + (size_t)(idx < 0 ? 0 : idx) * CI + g * 8;
        f32x4 v0 = *(const f32x4*)ip;
        f32x4 v1 = *(const f32x4*)(ip + 4);
        if (idx < 0) {
          v0 = (f32x4){0.f, 0.f, 0.f, 0.f};
          v1 = (f32x4){0.f, 0.f, 0.f, 0.f};
        }
        a[0] = (__bf16)v0[0]; a[1] = (__bf16)v0[1];
        a[2] = (__bf16)v0[2]; a[3] = (__bf16)v0[3];
        a[4] = (__bf16)v1[0]; a[5] = (__bf16)v1[1];
        a[6] = (__bf16)v1[2]; a[7] = (__bf16)v1[3];
      }
#pragma unroll
      for (int b = 0; b < 4; ++b)
        acc[t][b] = __builtin_amdgcn_mfma_f32_16x16x32_bf16(a, bf[b], acc[t][b], 0, 0, 0);
    }
  }
}

template <bool BF16IN>
__global__ __launch_bounds__(THREADS, 2) void octconv_kernel(
    const void* __restrict__ input_v,   // bf16[N][32] (ws) or f32[N][32]
    const float* __restrict__ weights,  // [27][32][64]
    const int*   __restrict__ neigh,    // [N][27]
    float*       __restrict__ out)      // [N][64]
{
  __shared__ ushort w_lds[KH * CO * WPAD];   // 71,680 B -> 2 blocks/CU

  const int tid  = threadIdx.x;
  const int wave = tid >> 6;
  const int lane = tid & 63;
  const int g    = lane >> 4;
  const int r16  = lane & 15;
  const int oct_base = blockIdx.x * OCT_PER_BLOCK + wave * (16 * TILE_T);

  f32x4 acc[TILE_T][4];
#pragma unroll
  for (int t = 0; t < TILE_T; ++t)
#pragma unroll
    for (int b = 0; b < 4; ++b)
      acc[t][b] = (f32x4){0.f, 0.f, 0.f, 0.f};

  // Phase 0: taps 0..13
  stage_weights<KH>(weights, w_lds, 0);
  __syncthreads();
  compute_phase<KH, BF16IN>(input_v, neigh, w_lds, oct_base, 0, g, r16, acc);
  __syncthreads();

  // Phase 1: taps 14..26
  stage_weights<KK - KH>(weights, w_lds, KH);
  __syncthreads();
  compute_phase<KK - KH, BF16IN>(input_v, neigh, w_lds, oct_base, KH, g, r16, acc);

  // C/D layout: col = lane&15, row = (lane>>4)*4 + reg
#pragma unroll
  for (int t = 0; t < TILE_T; ++t) {
    float* __restrict__ obase =
        out + (size_t)(oct_base + t * 16 + g * 4) * CO + r16;
#pragma unroll
    for (int rr = 0; rr < 4; ++rr) {
#pragma unroll
      for (int b = 0; b < 4; ++b)
        obase[rr * CO + 16 * b] = acc[t][b][rr];
    }
  }
}

extern "C" void kernel_launch(void* const* d_in, const int* in_sizes, int n_in,
                              void* d_out, int out_size, void* d_ws, size_t ws_size,
                              hipStream_t stream) {
  const float* input   = (const float*)d_in[0];
  const float* weights = (const float*)d_in[1];
  const int*   neigh   = (const int*)d_in[2];
  float*       out     = (float*)d_out;

  const size_t bf16_bytes = (size_t)NN * CI * sizeof(ushort);  // 16 MiB
  const bool use_bf16 = ws_size >= bf16_bytes;

  dim3 grid(NN / OCT_PER_BLOCK);   // 1024 blocks

  if (use_bf16) {
    ushort* in_bf16 = (ushort*)d_ws;
    cvt_input_kernel<<<dim3((NN * CI) / (256 * 4)), 256, 0, stream>>>(input, in_bf16);
    octconv_kernel<true><<<grid, THREADS, 0, stream>>>(in_bf16, weights, neigh, out);
  } else {
    octconv_kernel<false><<<grid, THREADS, 0, stream>>>(input, weights, neigh, out);
  }
}

// Round 4
// 152.191 us; speedup vs baseline: 1.1572x; 1.1572x over previous
//
#include <hip/hip_runtime.h>

// OctreeConv: out[N,64] = sum_k gather_k(input)[N,32] @ W[k][32,64]
// Round 4: explicit gather software-pipeline. 512-thr blocks (256-VGPR
// budget), 54 neigh idx preloaded, 4-deep rotating A-prefetch buffers,
// steady-state loop contains ONLY gather VMEM ops (vmcnt stays clean).

typedef float  f32x4  __attribute__((ext_vector_type(4)));
typedef __bf16 bf16x8 __attribute__((ext_vector_type(8)));
typedef int    i32x4  __attribute__((ext_vector_type(4)));
typedef ushort u16x4  __attribute__((ext_vector_type(4)));

#define NN 262144
#define CI 32
#define CO 64
#define KK 27
#define WPAD 40               // 80B rows: 16B-aligned b128 reads, low conflict
#define THREADS 512
#define TILE_T 2              // 2 A-tiles (32 octants) per wave
#define PF 4                  // prefetch depth in taps
#define OCT_PER_BLOCK (TILE_T * 16 * (THREADS / 64))   // 256

__device__ __forceinline__ ushort f2bf_rne(float f) {
  union { float f; unsigned u; } v; v.f = f;
  unsigned u = v.u;
  u += 0x7FFFu + ((u >> 16) & 1u);
  return (ushort)(u >> 16);
}

__global__ __launch_bounds__(256) void cvt_input_kernel(
    const float* __restrict__ in, ushort* __restrict__ out) {
  const int i = (blockIdx.x * 256 + threadIdx.x) * 4;
  f32x4 v = *(const f32x4*)(in + i);
  u16x4 o;
  o[0] = f2bf_rne(v[0]); o[1] = f2bf_rne(v[1]);
  o[2] = f2bf_rne(v[2]); o[3] = f2bf_rne(v[3]);
  *(u16x4*)(out + i) = o;
}

// raw 16B gather of channels [g*8, g*8+8) of row idx (clamped); no zeroing
__device__ __forceinline__ i32x4 gather16(const ushort* __restrict__ input,
                                          int idx, int g) {
  const ushort* p = input + (size_t)(idx < 0 ? 0 : idx) * CI + g * 8;
  return *(const i32x4*)p;
}

__global__ __launch_bounds__(THREADS, 2) void octconv_kernel(
    const ushort* __restrict__ input,   // bf16 [N][32] (in d_ws)
    const float* __restrict__ weights,  // [27][32][64]
    const int*   __restrict__ neigh,    // [N][27]
    float*       __restrict__ out)      // [N][64]
{
  __shared__ ushort w_lds[KK * CO * WPAD];   // 138,240 B -> 1 block/CU

  // ---- stage weights bf16 transposed to [k][o][c]; 27 iters/thread ----
  for (int i = threadIdx.x; i < KK * CO * (CI / 4); i += THREADS) {
    const int c4 = (i & 7) * 4;
    const int ko = i >> 3;          // k*CO + o
    const int k  = ko >> 6;
    const int o  = ko & 63;
    const float* wp = weights + ((size_t)k * CI + c4) * CO + o;
    u16x4 w;
    w[0] = f2bf_rne(wp[0 * CO]);
    w[1] = f2bf_rne(wp[1 * CO]);
    w[2] = f2bf_rne(wp[2 * CO]);
    w[3] = f2bf_rne(wp[3 * CO]);
    *(u16x4*)&w_lds[ko * WPAD + c4] = w;
  }

  const int wave = threadIdx.x >> 6;
  const int lane = threadIdx.x & 63;
  const int g    = lane >> 4;
  const int r16  = lane & 15;
  const int oct_base = blockIdx.x * OCT_PER_BLOCK + wave * (16 * TILE_T);

  // ---- preload ALL neighbor indices (54 VGPR) ----
  int nb[TILE_T][KK];
#pragma unroll
  for (int t = 0; t < TILE_T; ++t) {
    const int* __restrict__ nrow =
        neigh + (size_t)(oct_base + t * 16 + r16) * KK;
#pragma unroll
    for (int k = 0; k < KK; ++k) nb[t][k] = nrow[k];
  }

  __syncthreads();

  f32x4 acc[TILE_T][4];
#pragma unroll
  for (int t = 0; t < TILE_T; ++t)
#pragma unroll
    for (int b = 0; b < 4; ++b)
      acc[t][b] = (f32x4){0.f, 0.f, 0.f, 0.f};

  // ---- software pipeline: rotating 4-deep A buffers (static indexing) ----
  i32x4 abuf[PF][TILE_T];
#pragma unroll
  for (int k = 0; k < PF; ++k)
#pragma unroll
    for (int t = 0; t < TILE_T; ++t)
      abuf[k][t] = gather16(input, nb[t][k], g);

#pragma unroll
  for (int k = 0; k < KK; ++k) {
    // B fragments for this tap (LDS, lgkmcnt - independent counter)
    bf16x8 bf[4];
#pragma unroll
    for (int b = 0; b < 4; ++b)
      bf[b] = *(const bf16x8*)&w_lds[(k * CO + r16 + 16 * b) * WPAD + g * 8];

#pragma unroll
    for (int t = 0; t < TILE_T; ++t) {
      i32x4 v = abuf[k % PF][t];
      if (nb[t][k] < 0) v = (i32x4){0, 0, 0, 0};
      const bf16x8 a = __builtin_bit_cast(bf16x8, v);
#pragma unroll
      for (int b = 0; b < 4; ++b)
        acc[t][b] = __builtin_amdgcn_mfma_f32_16x16x32_bf16(a, bf[b], acc[t][b], 0, 0, 0);
    }

    // issue next prefetch into the slot just consumed
    if (k + PF < KK) {
#pragma unroll
      for (int t = 0; t < TILE_T; ++t)
        abuf[k % PF][t] = gather16(input, nb[t][k + PF], g);
    }
  }

  // ---- epilogue: C/D layout col = lane&15, row = (lane>>4)*4 + reg ----
#pragma unroll
  for (int t = 0; t < TILE_T; ++t) {
    float* __restrict__ obase =
        out + (size_t)(oct_base + t * 16 + g * 4) * CO + r16;
#pragma unroll
    for (int rr = 0; rr < 4; ++rr) {
#pragma unroll
      for (int b = 0; b < 4; ++b)
        obase[rr * CO + 16 * b] = acc[t][b][rr];
    }
  }
}

// fallback: fp32 gather with inline cvt (only if ws too small for bf16 copy)
__global__ __launch_bounds__(THREADS, 2) void octconv_kernel_f32(
    const float* __restrict__ input, const float* __restrict__ weights,
    const int* __restrict__ neigh, float* __restrict__ out)
{
  __shared__ ushort w_lds[KK * CO * WPAD];
  for (int i = threadIdx.x; i < KK * CO * (CI / 4); i += THREADS) {
    const int c4 = (i & 7) * 4;
    const int ko = i >> 3;
    const int k  = ko >> 6;
    const int o  = ko & 63;
    const float* wp = weights + ((size_t)k * CI + c4) * CO + o;
    u16x4 w;
    w[0] = f2bf_rne(wp[0 * CO]); w[1] = f2bf_rne(wp[1 * CO]);
    w[2] = f2bf_rne(wp[2 * CO]); w[3] = f2bf_rne(wp[3 * CO]);
    *(u16x4*)&w_lds[ko * WPAD + c4] = w;
  }
  const int wave = threadIdx.x >> 6;
  const int lane = threadIdx.x & 63;
  const int g = lane >> 4, r16 = lane & 15;
  const int oct_base = blockIdx.x * OCT_PER_BLOCK + wave * (16 * TILE_T);
  __syncthreads();
  f32x4 acc[TILE_T][4];
#pragma unroll
  for (int t = 0; t < TILE_T; ++t)
#pragma unroll
    for (int b = 0; b < 4; ++b) acc[t][b] = (f32x4){0.f,0.f,0.f,0.f};
#pragma unroll
  for (int t = 0; t < TILE_T; ++t) {
    const int* nrow = neigh + (size_t)(oct_base + t * 16 + r16) * KK;
    for (int k = 0; k < KK; ++k) {
      const int idx = nrow[k];
      const float* ip = input + (size_t)(idx < 0 ? 0 : idx) * CI + g * 8;
      f32x4 v0 = *(const f32x4*)ip, v1 = *(const f32x4*)(ip + 4);
      if (idx < 0) { v0 = (f32x4){0,0,0,0}; v1 = (f32x4){0,0,0,0}; }
      bf16x8 a;
      a[0]=(__bf16)v0[0]; a[1]=(__bf16)v0[1]; a[2]=(__bf16)v0[2]; a[3]=(__bf16)v0[3];
      a[4]=(__bf16)v1[0]; a[5]=(__bf16)v1[1]; a[6]=(__bf16)v1[2]; a[7]=(__bf16)v1[3];
#pragma unroll
      for (int b = 0; b < 4; ++b) {
        const bf16x8 bfb = *(const bf16x8*)&w_lds[(k * CO + r16 + 16 * b) * WPAD + g * 8];
        acc[t][b] = __builtin_amdgcn_mfma_f32_16x16x32_bf16(a, bfb, acc[t][b], 0, 0, 0);
      }
    }
  }
#pragma unroll
  for (int t = 0; t < TILE_T; ++t) {
    float* obase = out + (size_t)(oct_base + t * 16 + g * 4) * CO + r16;
#pragma unroll
    for (int rr = 0; rr < 4; ++rr)
#pragma unroll
      for (int b = 0; b < 4; ++b) obase[rr * CO + 16 * b] = acc[t][b][rr];
  }
}

extern "C" void kernel_launch(void* const* d_in, const int* in_sizes, int n_in,
                              void* d_out, int out_size, void* d_ws, size_t ws_size,
                              hipStream_t stream) {
  const float* input   = (const float*)d_in[0];
  const float* weights = (const float*)d_in[1];
  const int*   neigh   = (const int*)d_in[2];
  float*       out     = (float*)d_out;

  const size_t bf16_bytes = (size_t)NN * CI * sizeof(ushort);  // 16 MiB
  dim3 grid(NN / OCT_PER_BLOCK);   // 1024 blocks

  if (ws_size >= bf16_bytes) {
    ushort* in_bf16 = (ushort*)d_ws;
    cvt_input_kernel<<<dim3((NN * CI) / (256 * 4)), 256, 0, stream>>>(input, in_bf16);
    octconv_kernel<<<grid, THREADS, 0, stream>>>(in_bf16, weights, neigh, out);
  } else {
    octconv_kernel_f32<<<grid, THREADS, 0, stream>>>(input, weights, neigh, out);
  }
}

// Round 5
// 114.152 us; speedup vs baseline: 1.5428x; 1.3332x over previous
//
#include <hip/hip_runtime.h>

// OctreeConv: out[N,64] = sum_k gather_k(input)[N,32] @ W[k][32,64]
// Round 5: concurrency attack. 16 waves/CU (1024-thr block, compact 110.6KB
// weights LDS) x PF=12-deep gather pipeline = 192KB in flight/CU (3x R4).
// Zero-row trick: invalid neighbors gather from an appended zero row, so the
// inner loop is {load dwordx4 via u32 voffset -> 4 ds_read -> 4 MFMA} only.

typedef float  f32x4  __attribute__((ext_vector_type(4)));
typedef __bf16 bf16x8 __attribute__((ext_vector_type(8)));
typedef int    i32x4  __attribute__((ext_vector_type(4)));
typedef ushort u16x4  __attribute__((ext_vector_type(4)));
typedef ushort u16x8  __attribute__((ext_vector_type(8)));

#define NN 262144
#define CI 32
#define CO 64
#define KK 27
#define THREADS 1024
#define PF 12                 // gather prefetch depth (taps)
#define OCT_PER_BLOCK 256     // 16 waves x 16 octants

__device__ __forceinline__ ushort f2bf_rne(float f) {
  union { float f; unsigned u; } v; v.f = f;
  unsigned u = v.u;
  u += 0x7FFFu + ((u >> 16) & 1u);
  return (ushort)(u >> 16);
}

// fp32 -> bf16 pre-pass; block (NN*CI/1024) additionally writes a zero row
// at index NN (gather target for invalid neighbors).
__global__ __launch_bounds__(256) void cvt_input_kernel(
    const float* __restrict__ in, ushort* __restrict__ out) {
  const int bid = blockIdx.x;
  if (bid == (NN * CI) / 1024) {
    if (threadIdx.x < 8) {
      u16x4 z = {0, 0, 0, 0};
      *(u16x4*)(out + (size_t)NN * CI + threadIdx.x * 4) = z;
    }
    return;
  }
  const int i = (bid * 256 + threadIdx.x) * 4;
  f32x4 v = *(const f32x4*)(in + i);
  u16x4 o;
  o[0] = f2bf_rne(v[0]); o[1] = f2bf_rne(v[1]);
  o[2] = f2bf_rne(v[2]); o[3] = f2bf_rne(v[3]);
  *(u16x4*)(out + i) = o;
}

__global__ __launch_bounds__(THREADS, 4) void octconv_kernel(
    const ushort* __restrict__ input,   // bf16 [NN+1][32] in d_ws (row NN = 0)
    const float* __restrict__ weights,  // [27][32][64] fp32
    const int*   __restrict__ neigh,    // [N][27]
    float*       __restrict__ out)      // [N][64]
{
  // Compact weights: [k][g][o] of 8-channel bf16 vectors, 16B each.
  // Fragment read: 16B at ((k*4+g)*64 + r16 + 16b)*16 -> bank=(o*4)%32, 2-way max.
  __shared__ ushort w_lds[KK * 4 * CO * 8];   // 110,592 B -> 16 waves/CU

  for (int i = threadIdx.x; i < KK * 4 * CO; i += THREADS) {
    const int k = i >> 8;
    const int g = (i >> 6) & 3;
    const int o = i & 63;
    const float* wp = weights + ((size_t)k * CI + g * 8) * CO + o;
    u16x8 w;
#pragma unroll
    for (int j = 0; j < 8; ++j) w[j] = f2bf_rne(wp[j * CO]);
    *(u16x8*)&w_lds[i * 8] = w;
  }

  const int lane = threadIdx.x & 63;
  const int wave = threadIdx.x >> 6;
  const int g    = lane >> 4;
  const int r16  = lane & 15;
  const int oct_base = blockIdx.x * OCT_PER_BLOCK + wave * 16;

  // Per-lane u32 byte offsets for all 27 gathers (invalid -> zero row NN).
  uint32_t voff[KK];
  {
    const int* __restrict__ nrow = neigh + (size_t)(oct_base + r16) * KK;
#pragma unroll
    for (int k = 0; k < KK; ++k) {
      const int idx = nrow[k];
      voff[k] = ((uint32_t)(idx < 0 ? NN : idx) << 6) + g * 16;
    }
  }

  __syncthreads();

  f32x4 acc[4];
#pragma unroll
  for (int b = 0; b < 4; ++b) acc[b] = (f32x4){0.f, 0.f, 0.f, 0.f};

  const char* __restrict__ ibase = (const char*)input;

  // 12-deep rotating gather pipeline (fully unrolled -> static indices).
  i32x4 abuf[PF];
#pragma unroll
  for (int k = 0; k < PF; ++k)
    abuf[k] = *(const i32x4*)(ibase + voff[k]);

#pragma unroll
  for (int k = 0; k < KK; ++k) {
    const bf16x8 a = __builtin_bit_cast(bf16x8, abuf[k % PF]);
    const ushort* __restrict__ wk = &w_lds[(k * 4 + g) * (CO * 8) + r16 * 8];
#pragma unroll
    for (int b = 0; b < 4; ++b) {
      const bf16x8 bf = *(const bf16x8*)(wk + b * 128);   // +16 outputs
      acc[b] = __builtin_amdgcn_mfma_f32_16x16x32_bf16(a, bf, acc[b], 0, 0, 0);
    }
    if (k + PF < KK)
      abuf[k % PF] = *(const i32x4*)(ibase + voff[k + PF]);
  }

  // C/D layout: col = lane&15, row = (lane>>4)*4 + reg
  float* __restrict__ obase = out + (size_t)(oct_base + g * 4) * CO + r16;
#pragma unroll
  for (int rr = 0; rr < 4; ++rr)
#pragma unroll
    for (int b = 0; b < 4; ++b)
      obase[rr * CO + 16 * b] = acc[b][rr];
}

// Fallback (ws too small for bf16 copy): fp32 gather + inline cvt, no pipeline.
__global__ __launch_bounds__(THREADS, 4) void octconv_kernel_f32(
    const float* __restrict__ input, const float* __restrict__ weights,
    const int* __restrict__ neigh, float* __restrict__ out)
{
  __shared__ ushort w_lds[KK * 4 * CO * 8];
  for (int i = threadIdx.x; i < KK * 4 * CO; i += THREADS) {
    const int k = i >> 8;
    const int g = (i >> 6) & 3;
    const int o = i & 63;
    const float* wp = weights + ((size_t)k * CI + g * 8) * CO + o;
    u16x8 w;
#pragma unroll
    for (int j = 0; j < 8; ++j) w[j] = f2bf_rne(wp[j * CO]);
    *(u16x8*)&w_lds[i * 8] = w;
  }
  const int lane = threadIdx.x & 63;
  const int wave = threadIdx.x >> 6;
  const int g = lane >> 4, r16 = lane & 15;
  const int oct_base = blockIdx.x * OCT_PER_BLOCK + wave * 16;
  const int* __restrict__ nrow = neigh + (size_t)(oct_base + r16) * KK;
  __syncthreads();
  f32x4 acc[4];
#pragma unroll
  for (int b = 0; b < 4; ++b) acc[b] = (f32x4){0.f, 0.f, 0.f, 0.f};
#pragma unroll
  for (int k = 0; k < KK; ++k) {
    const int idx = nrow[k];
    const float* ip = input + (size_t)(idx < 0 ? 0 : idx) * CI + g * 8;
    f32x4 v0 = *(const f32x4*)ip, v1 = *(const f32x4*)(ip + 4);
    if (idx < 0) { v0 = (f32x4){0,0,0,0}; v1 = (f32x4){0,0,0,0}; }
    bf16x8 a;
    a[0]=(__bf16)v0[0]; a[1]=(__bf16)v0[1]; a[2]=(__bf16)v0[2]; a[3]=(__bf16)v0[3];
    a[4]=(__bf16)v1[0]; a[5]=(__bf16)v1[1]; a[6]=(__bf16)v1[2]; a[7]=(__bf16)v1[3];
    const ushort* wk = &w_lds[(k * 4 + g) * (CO * 8) + r16 * 8];
#pragma unroll
    for (int b = 0; b < 4; ++b) {
      const bf16x8 bf = *(const bf16x8*)(wk + b * 128);
      acc[b] = __builtin_amdgcn_mfma_f32_16x16x32_bf16(a, bf, acc[b], 0, 0, 0);
    }
  }
  float* obase = out + (size_t)(oct_base + g * 4) * CO + r16;
#pragma unroll
  for (int rr = 0; rr < 4; ++rr)
#pragma unroll
    for (int b = 0; b < 4; ++b)
      obase[rr * CO + 16 * b] = acc[b][rr];
}

extern "C" void kernel_launch(void* const* d_in, const int* in_sizes, int n_in,
                              void* d_out, int out_size, void* d_ws, size_t ws_size,
                              hipStream_t stream) {
  const float* input   = (const float*)d_in[0];
  const float* weights = (const float*)d_in[1];
  const int*   neigh   = (const int*)d_in[2];
  float*       out     = (float*)d_out;

  const size_t bf16_bytes = ((size_t)NN + 1) * CI * sizeof(ushort);  // 16 MiB + row
  dim3 grid(NN / OCT_PER_BLOCK);   // 1024 blocks

  if (ws_size >= bf16_bytes) {
    ushort* in_bf16 = (ushort*)d_ws;
    cvt_input_kernel<<<dim3((NN * CI) / 1024 + 1), 256, 0, stream>>>(input, in_bf16);
    octconv_kernel<<<grid, THREADS, 0, stream>>>(in_bf16, weights, neigh, out);
  } else {
    octconv_kernel_f32<<<grid, THREADS, 0, stream>>>(input, weights, neigh, out);
  }
}